// Round 18
// baseline (49.048 us; speedup 1.0000x reference)
//
#include <hip/hip_runtime.h>

#define BS 256

typedef float f32x2 __attribute__((ext_vector_type(2)));

__device__ __forceinline__ float fast_acos(float x) {
    // Abramowitz & Stegun 4.4.45, branchless; |err| <= ~6.8e-5 rad.
    float ax = fabsf(x);
    float s  = sqrtf(fmaxf(0.f, 1.f - ax));
    float p  = fmaf(ax, fmaf(ax, fmaf(ax, -0.0187293f, 0.0742610f), -0.2121144f), 1.5707288f);
    float r  = s * p;
    return (x >= 0.f) ? r : 3.14159265358979f - r;
}

// (x,y)-packed corner math: every sub/mul/fma is a <2 x float> op -> VOP3P
// v_pk_* on gfx950 (2 lanes/instruction). Results bit-identical to scalar.
__device__ __forceinline__ float dir_item(float4 L, float4 O, float4 Tn, bool first) {
    f32x2 LA = {L.x, L.y},  LB = {L.z, L.w};
    f32x2 OA = {O.x, O.y},  OB = {O.z, O.w};
    f32x2 TA = {Tn.x, Tn.y}, TB = {Tn.z, Tn.w};

    f32x2 PA = LA + OA, PB = LB + OB;
    f32x2 P0 = PA - 0.5f * PB, P1 = PA;          // pred_c corners
    f32x2 T0 = TA - 0.5f * TB, T1 = TA;          // true_c corners
    f32x2 Lc1 = LA - 0.5f * LB;                  // conv once
    f32x2 L0, L1;
    if (first) { L0 = Lc1; L1 = LA; }
    else       { L0 = 0.5f * (LA - LB); L1 = Lc1; }

    // 5 corner points: center, (x0,y0), (x0,y1), (x1,y0), (x1,y1)
    f32x2 l[5] = {0.5f * (L0 + L1), L0, {L0.x, L1.y}, {L1.x, L0.y}, L1};
    f32x2 p[5] = {0.5f * (P0 + P1), P0, {P0.x, P1.y}, {P1.x, P0.y}, P1};
    f32x2 t[5] = {0.5f * (T0 + T1), T0, {T0.x, T1.y}, {T1.x, T0.y}, T1};

    float acc = 0.f;
    #pragma unroll
    for (int k = 0; k < 5; ++k) {
        f32x2 dp = p[k] - l[k];
        f32x2 dt = t[k] - l[k];
        f32x2 sp = dp * dp;
        f32x2 st = dt * dt;
        f32x2 dv = dp * dt;
        float p2  = sp.x + sp.y;
        float t2  = st.x + st.y;
        float dot = dv.x + dv.y;
        float inv = rsqrtf(p2 * t2);   // ref's +1e-6 eps shifts cos by <=1e-5: within budget
        float cosang = fminf(1.0f, fmaxf(-1.0f, dot * inv));
        acc += fast_acos(cosang);
    }
    return acc;
}

__device__ __forceinline__ float sl1_4(float4 O, float4 D) {
    float s = 0.f;
    { float d = O.x - D.x, ad = fabsf(d); s += (ad < 1.f) ? 0.5f * d * d : ad - 0.5f; }
    { float d = O.y - D.y, ad = fabsf(d); s += (ad < 1.f) ? 0.5f * d * d : ad - 0.5f; }
    { float d = O.z - D.z, ad = fabsf(d); s += (ad < 1.f) ? 0.5f * d * d : ad - 0.5f; }
    { float d = O.w - D.w, ad = fabsf(d); s += (ad < 1.f) ? 0.5f * d * d : ad - 0.5f; }
    return s;
}

#define LD4(ptr) (*reinterpret_cast<const float4*>(ptr))

// One thread owns one p for 4 frames (grp g: t = 4g..4g+3).
__global__ __launch_bounds__(BS)
void fused_kernel(const float* __restrict__ outputs,
                  const float* __restrict__ targets,
                  float* __restrict__ out,
                  float* __restrict__ partials,
                  int P, float w) {
    __shared__ float smem[BS / 64];
    long long gid = (long long)blockIdx.x * BS + threadIdx.x;
    float acc = 0.f;
    if (gid < 4ll * P) {
        int grp     = (int)(gid / P);          // 0..3
        long long p = gid - (long long)grp * P;
        const long long ts8 = 8ll * P, os4 = 4ll * P;
        const float* tb = targets + ((long long)(grp * 4) * P + p) * 8;
        const float* ob = outputs + ((long long)(grp * 4) * P + p) * 4;
        float*       wb = out + (long long)(grp * 4) * P + p;
        const bool has4 = (grp < 3);

        float4 Tf0 = LD4(tb);
        float4 Tf1 = LD4(tb + ts8);
        float4 Tf2 = LD4(tb + 2 * ts8);
        float4 Tf3 = LD4(tb + 3 * ts8);
        float4 Ts0 = LD4(tb + 4);
        float4 Ts1 = LD4(tb + ts8 + 4);
        float4 Ts2 = LD4(tb + 2 * ts8 + 4);
        float4 Ts3 = LD4(tb + 3 * ts8 + 4);
        float4 O0  = LD4(ob);
        float4 O1  = LD4(ob + os4);
        float4 O2  = LD4(ob + 2 * os4);
        float4 O3  = LD4(ob + 3 * os4);
        float4 Tf4 = has4 ? LD4(tb + 4 * ts8) : make_float4(0.f, 0.f, 0.f, 0.f);

        // smooth-L1 part (finalize adds the dir constant, L2-locally)
        wb[0]       = sl1_4(O0, Ts0) * w;
        wb[P]       = sl1_4(O1, Ts1) * w;
        wb[2ll * P] = sl1_4(O2, Ts2) * w;
        wb[3ll * P] = sl1_4(O3, Ts3) * w;

        acc  = dir_item(Tf0, O0, Tf1, grp == 0);
        acc += dir_item(Tf1, O1, Tf2, false);
        acc += dir_item(Tf2, O2, Tf3, false);
        if (has4) acc += dir_item(Tf3, O3, Tf4, false);
    }
    #pragma unroll
    for (int off = 32; off > 0; off >>= 1) acc += __shfl_down(acc, off, 64);
    int lane = threadIdx.x & 63, w64 = threadIdx.x >> 6;
    if (lane == 0) smem[w64] = acc;
    __syncthreads();
    if (threadIdx.x == 0) {
        float r = 0.f;
        #pragma unroll
        for (int i = 0; i < BS / 64; ++i) r += smem[i];
        partials[blockIdx.x] = r;
    }
}

// Producer-matched geometry: same grid/block mapping as fused_kernel, so each
// thread re-touches exactly the 4 floats its twin wrote -> same blockIdx ->
// same XCD (round-robin dispatch) -> the RMW hits per-XCD L2, not HBM.
__global__ __launch_bounds__(BS)
void finalize_kernel(const float* __restrict__ partials, int nb,
                     float* __restrict__ out, int P) {
    __shared__ double dsm[BS / 64];
    __shared__ float c_sh;
    double dacc = 0.0;
    for (int i = threadIdx.x; i < nb; i += BS) dacc += (double)partials[i];
    #pragma unroll
    for (int off = 32; off > 0; off >>= 1) dacc += __shfl_down(dacc, off, 64);
    int lane = threadIdx.x & 63, wv = threadIdx.x >> 6;
    if (lane == 0) dsm[wv] = dacc;
    __syncthreads();
    if (threadIdx.x == 0) {
        double tot = dsm[0] + dsm[1] + dsm[2] + dsm[3];
        c_sh = (float)(0.01 * 0.2 * tot / ((double)P * 15.0));
    }
    __syncthreads();
    float c = c_sh;

    long long gid = (long long)blockIdx.x * BS + threadIdx.x;
    if (gid < 4ll * P) {
        int grp     = (int)(gid / P);
        long long p = gid - (long long)grp * P;
        float* wb = out + (long long)(grp * 4) * P + p;
        wb[0]       += c;
        wb[P]       += c;
        wb[2ll * P] += c;
        wb[3ll * P] += c;
    }
}

extern "C" void kernel_launch(void* const* d_in, const int* in_sizes, int n_in,
                              void* d_out, int out_size, void* d_ws, size_t ws_size,
                              hipStream_t stream) {
    const float* outputs = (const float*)d_in[0];
    const float* targets = (const float*)d_in[1];
    float* out = (float*)d_out;
    float* partials = (float*)d_ws;

    const int T = 16;
    int P = in_sizes[0] / (T * 4);                 // 200000

    long long units = 4ll * P;                     // 800,000
    int nb1 = (int)((units + BS - 1) / BS);        // 3125 blocks

    fused_kernel<<<nb1, BS, 0, stream>>>(outputs, targets, out, partials,
                                         P, 0.99f / (float)P);
    finalize_kernel<<<nb1, BS, 0, stream>>>(partials, nb1, out, P);
}

// Round 19
// 42.626 us; speedup vs baseline: 1.1507x; 1.1507x over previous
//
#include <hip/hip_runtime.h>

#define BS 256
#define LD4(ptr) (*reinterpret_cast<const float4*>(ptr))

__device__ __forceinline__ float fast_acos(float x) {
    // Abramowitz & Stegun 4.4.45; raw v_sqrt (arg in [0,1], no fixup needed).
    // |err| <= ~6.8e-5 rad; output weight 0.002 -> error contribution <= 2e-7.
    float ax = fabsf(x);
    float s  = __builtin_amdgcn_sqrtf(fmaxf(0.f, 1.f - ax));
    float p  = fmaf(ax, fmaf(ax, fmaf(ax, -0.0187293f, 0.0742610f), -0.2121144f), 1.5707288f);
    float r  = s * p;
    return (x >= 0.f) ? r : 3.14159265358979f - r;
}

__device__ __forceinline__ float ang(float p2, float t2, float dot) {
    float inv = __builtin_amdgcn_rsqf(p2 * t2);   // raw v_rsq: 1 instr
    float c   = __builtin_amdgcn_fmed3f(dot * inv, -1.f, 1.f);
    return fast_acos(c);
}

// Shared-subexpression corner math: 8 diffs, 8 squares, 4 cross-products are
// computed ONCE; each of the 4 box corners is then 3 adds + ang(), the center
// reuses half-sum diffs. ~30% fewer VALU ops than the per-corner form.
__device__ __forceinline__ float dir_item(float4 L, float4 O, float4 Tn, bool first) {
    float pa = L.x + O.x, pb = L.y + O.y;
    float Px0 = pa - 0.5f * (L.z + O.z), Py0 = pb - 0.5f * (L.w + O.w);
    float Px1 = pa, Py1 = pb;
    float Tx0 = Tn.x - 0.5f * Tn.z, Ty0 = Tn.y - 0.5f * Tn.w;
    float Tx1 = Tn.x, Ty1 = Tn.y;
    float Lx1 = L.x - 0.5f * L.z, Ly1 = L.y - 0.5f * L.w;
    float Lx0, Ly0;
    if (first) { Lx0 = Lx1; Ly0 = Ly1; Lx1 = L.x; Ly1 = L.y; }
    else       { Lx0 = 0.5f * (L.x - L.z); Ly0 = 0.5f * (L.y - L.w); }

    // shared diffs (pred-last = a, true-last = b)
    float ax0 = Px0 - Lx0, ax1 = Px1 - Lx1, ay0 = Py0 - Ly0, ay1 = Py1 - Ly1;
    float bx0 = Tx0 - Lx0, bx1 = Tx1 - Lx1, by0 = Ty0 - Ly0, by1 = Ty1 - Ly1;
    float acx = 0.5f * (ax0 + ax1), acy = 0.5f * (ay0 + ay1);
    float bcx = 0.5f * (bx0 + bx1), bcy = 0.5f * (by0 + by1);
    // shared squares and cross-products
    float sax0 = ax0 * ax0, sax1 = ax1 * ax1, say0 = ay0 * ay0, say1 = ay1 * ay1;
    float sbx0 = bx0 * bx0, sbx1 = bx1 * bx1, sby0 = by0 * by0, sby1 = by1 * by1;
    float cx0 = ax0 * bx0, cx1 = ax1 * bx1, cy0 = ay0 * by0, cy1 = ay1 * by1;

    // corners: center, (x0,y0), (x0,y1), (x1,y0), (x1,y1)
    float acc;
    acc  = ang(fmaf(acx, acx, acy * acy), fmaf(bcx, bcx, bcy * bcy),
               fmaf(acx, bcx, acy * bcy));
    acc += ang(sax0 + say0, sbx0 + sby0, cx0 + cy0);
    acc += ang(sax0 + say1, sbx0 + sby1, cx0 + cy1);
    acc += ang(sax1 + say0, sbx1 + sby0, cx1 + cy0);
    acc += ang(sax1 + say1, sbx1 + sby1, cx1 + cy1);
    return acc;
}

__device__ __forceinline__ float sl1_4(float4 O, float4 D) {
    float s = 0.f;
    { float d = O.x - D.x, ad = fabsf(d); s += (ad < 1.f) ? 0.5f * d * d : ad - 0.5f; }
    { float d = O.y - D.y, ad = fabsf(d); s += (ad < 1.f) ? 0.5f * d * d : ad - 0.5f; }
    { float d = O.z - D.z, ad = fabsf(d); s += (ad < 1.f) ? 0.5f * d * d : ad - 0.5f; }
    { float d = O.w - D.w, ad = fabsf(d); s += (ad < 1.f) ? 0.5f * d * d : ad - 0.5f; }
    return s;
}

// One thread owns one p for 4 frames (grp g: t = 4g..4g+3).
__global__ __launch_bounds__(BS)
void fused_kernel(const float* __restrict__ outputs,
                  const float* __restrict__ targets,
                  float* __restrict__ out,
                  float* __restrict__ partials,
                  int P, float w) {
    __shared__ float smem[BS / 64];
    long long gid = (long long)blockIdx.x * BS + threadIdx.x;
    float acc = 0.f;
    if (gid < 4ll * P) {
        int grp     = (int)(gid / P);          // 0..3
        long long p = gid - (long long)grp * P;
        const long long ts8 = 8ll * P, os4 = 4ll * P;
        const float* tb = targets + ((long long)(grp * 4) * P + p) * 8;
        const float* ob = outputs + ((long long)(grp * 4) * P + p) * 4;
        float*       wb = out + (long long)(grp * 4) * P + p;
        const bool has4 = (grp < 3);

        float4 Tf0 = LD4(tb);
        float4 Tf1 = LD4(tb + ts8);
        float4 Tf2 = LD4(tb + 2 * ts8);
        float4 Tf3 = LD4(tb + 3 * ts8);
        float4 Ts0 = LD4(tb + 4);
        float4 Ts1 = LD4(tb + ts8 + 4);
        float4 Ts2 = LD4(tb + 2 * ts8 + 4);
        float4 Ts3 = LD4(tb + 3 * ts8 + 4);
        float4 O0  = LD4(ob);
        float4 O1  = LD4(ob + os4);
        float4 O2  = LD4(ob + 2 * os4);
        float4 O3  = LD4(ob + 3 * os4);
        float4 Tf4 = has4 ? LD4(tb + 4 * ts8) : make_float4(0.f, 0.f, 0.f, 0.f);

        // smooth-L1 part (finalize adds the dir constant)
        wb[0]       = sl1_4(O0, Ts0) * w;
        wb[P]       = sl1_4(O1, Ts1) * w;
        wb[2ll * P] = sl1_4(O2, Ts2) * w;
        wb[3ll * P] = sl1_4(O3, Ts3) * w;

        acc  = dir_item(Tf0, O0, Tf1, grp == 0);
        acc += dir_item(Tf1, O1, Tf2, false);
        acc += dir_item(Tf2, O2, Tf3, false);
        if (has4) acc += dir_item(Tf3, O3, Tf4, false);
    }
    #pragma unroll
    for (int off = 32; off > 0; off >>= 1) acc += __shfl_down(acc, off, 64);
    int lane = threadIdx.x & 63, w64 = threadIdx.x >> 6;
    if (lane == 0) smem[w64] = acc;
    __syncthreads();
    if (threadIdx.x == 0) {
        float r = 0.f;
        #pragma unroll
        for (int i = 0; i < BS / 64; ++i) r += smem[i];
        partials[blockIdx.x] = r;
    }
}

__global__ void finalize_kernel(const float* __restrict__ partials, int nb,
                                float* __restrict__ out, long long n4, int P) {
    __shared__ double dsm[BS / 64];
    __shared__ float c_sh;
    double dacc = 0.0;
    for (int i = threadIdx.x; i < nb; i += BS) dacc += (double)partials[i];
    #pragma unroll
    for (int off = 32; off > 0; off >>= 1) dacc += __shfl_down(dacc, off, 64);
    int lane = threadIdx.x & 63, w = threadIdx.x >> 6;
    if (lane == 0) dsm[w] = dacc;
    __syncthreads();
    if (threadIdx.x == 0) {
        double tot = dsm[0] + dsm[1] + dsm[2] + dsm[3];
        c_sh = (float)(0.01 * 0.2 * tot / ((double)P * 15.0));
    }
    __syncthreads();
    float c = c_sh;

    float4* o4 = reinterpret_cast<float4*>(out);
    long long stride = (long long)gridDim.x * blockDim.x;
    for (long long i = (long long)blockIdx.x * blockDim.x + threadIdx.x; i < n4; i += stride) {
        float4 v = o4[i];
        v.x += c; v.y += c; v.z += c; v.w += c;
        o4[i] = v;
    }
}

extern "C" void kernel_launch(void* const* d_in, const int* in_sizes, int n_in,
                              void* d_out, int out_size, void* d_ws, size_t ws_size,
                              hipStream_t stream) {
    const float* outputs = (const float*)d_in[0];
    const float* targets = (const float*)d_in[1];
    float* out = (float*)d_out;
    float* partials = (float*)d_ws;

    const int T = 16;
    int P = in_sizes[0] / (T * 4);                 // 200000

    long long units = 4ll * P;                     // 800,000
    int nb1 = (int)((units + BS - 1) / BS);        // 3125 blocks

    fused_kernel<<<nb1, BS, 0, stream>>>(outputs, targets, out, partials,
                                         P, 0.99f / (float)P);

    long long n4 = (long long)out_size / 4;        // 16P/4
    int nb2 = (int)((n4 + BS - 1) / BS);
    if (nb2 > 2048) nb2 = 2048;
    finalize_kernel<<<nb2, BS, 0, stream>>>(partials, nb1, out, n4, P);
}